// Round 7
// baseline (407.985 us; speedup 1.0000x reference)
//
#include <hip/hip_runtime.h>
#include <hip/hip_bf16.h>

typedef unsigned short u16;
typedef unsigned int u32;
typedef __attribute__((ext_vector_type(8))) short bf16x8;
typedef __attribute__((ext_vector_type(4))) float f32x4;

#define T_TOK 8192
#define DIN 4096
#define DOUT 4096
#define N_SEQS 4
#define N_ADPT 8
#define MAXR 64
#define CACHE_LEN 512

__device__ __forceinline__ u16 f2bf(float f) {
    u32 u = __builtin_bit_cast(u32, f);
    u += 0x7fffu + ((u >> 16) & 1u);   // RNE
    return (u16)(u >> 16);
}

__device__ __forceinline__ void load_lds16(const u16* g, u16* l) {
    __builtin_amdgcn_global_load_lds(
        (const __attribute__((address_space(1))) u32*)g,
        (__attribute__((address_space(3))) u32*)l, 16, 0, 0);
}

// ---------------- fp32 -> bf16 convert (vectorized) ----------------
__global__ void cvt_kernel(const float* __restrict__ in, u16* __restrict__ out, int n4) {
    int i = blockIdx.x * blockDim.x + threadIdx.x;
    int stride = gridDim.x * blockDim.x;
    for (; i < n4; i += stride) {
        float4 v = reinterpret_cast<const float4*>(in)[i];
        ushort4 o;
        o.x = f2bf(v.x); o.y = f2bf(v.y); o.z = f2bf(v.z); o.w = f2bf(v.w);
        reinterpret_cast<ushort4*>(out)[i] = o;
    }
}

// ------------- build Bt[a][n][r] bf16 from b_cache via page table -------------
__global__ void build_bt(const float* __restrict__ b_cache, const int* __restrict__ rpt,
                         u16* __restrict__ Bt) {
    int id = blockIdx.x * 256 + threadIdx.x;      // total 8*8*4096 = 262144
    int n  = id & (DOUT - 1);
    int rb = (id >> 12) & 7;
    int a  = id >> 15;
    union { u16 u[8]; uint4 v; } pack;
    #pragma unroll
    for (int j = 0; j < 8; ++j) {
        int r = rb * 8 + j;
        int page = rpt[a * MAXR + r];
        pack.u[j] = f2bf(b_cache[(long)page * DOUT + n]);
    }
    *reinterpret_cast<uint4*>(&Bt[((long)(a * DOUT + n)) * MAXR + rb * 8]) = pack.v;
}

// ------------- xa[t][r] = scale * (x[t] . A[page(adapter,r)]), masked -------------
__launch_bounds__(256)
__global__ void xa_kernel(const u16* __restrict__ xb, const u16* __restrict__ ab,
                          const int* __restrict__ b_start_loc,
                          const int* __restrict__ b_adapter_ids,
                          const float* __restrict__ b_scaling,
                          const int* __restrict__ rpt,
                          const int* __restrict__ ranks,
                          u16* __restrict__ xa) {
    int t0 = blockIdx.x * 128;
    int seg = 0;
    #pragma unroll
    for (int i = 1; i < N_SEQS; ++i) if (b_start_loc[i] <= t0) seg = i;
    int adapter = b_adapter_ids[seg];
    float scale = b_scaling[seg];
    int rank = ranks[adapter];

    __shared__ __attribute__((aligned(16))) u16 As[128 * 32];
    __shared__ __attribute__((aligned(16))) u16 Bs[64 * 32];

    int tid = threadIdx.x;
    int lane = tid & 63, wave = tid >> 6;
    int lr = lane & 15, lk = lane >> 4;

    int e0 = wave * 64 + lane;               // [0,256)
    int e1 = 256 + e0;                       // [256,512)
    int ra0 = e0 >> 2, ca0 = (e0 & 3) * 8;
    int ra1 = e1 >> 2, ca1 = (e1 & 3) * 8;
    const u16* gA0 = xb + (long)(t0 + ra0) * DIN + ca0;
    const u16* gA1 = xb + (long)(t0 + ra1) * DIN + ca1;
    int rB = ra0;
    int page = rpt[adapter * MAXR + rB];
    const u16* gB = ab + (long)page * DIN + ca0;

    f32x4 acc[2][4] = {};

    for (int k0 = 0; k0 < DIN; k0 += 32) {
        load_lds16(gA0 + k0, As + wave * 512);
        load_lds16(gA1 + k0, As + 2048 + wave * 512);
        load_lds16(gB + k0,  Bs + wave * 512);
        asm volatile("s_waitcnt vmcnt(0)" ::: "memory");
        __syncthreads();
        bf16x8 af[2], bfr[4];
        #pragma unroll
        for (int m = 0; m < 2; ++m)
            af[m] = *(const bf16x8*)&As[(wave * 32 + m * 16 + lr) * 32 + lk * 8];
        #pragma unroll
        for (int n = 0; n < 4; ++n)
            bfr[n] = *(const bf16x8*)&Bs[(n * 16 + lr) * 32 + lk * 8];
        #pragma unroll
        for (int m = 0; m < 2; ++m)
            #pragma unroll
            for (int n = 0; n < 4; ++n)
                acc[m][n] = __builtin_amdgcn_mfma_f32_16x16x32_bf16(af[m], bfr[n], acc[m][n], 0, 0, 0);
        __syncthreads();
    }

    #pragma unroll
    for (int m = 0; m < 2; ++m) {
        int trow = t0 + wave * 32 + m * 16 + lk * 4;
        #pragma unroll
        for (int n = 0; n < 4; ++n) {
            int r = n * 16 + lr;
            #pragma unroll
            for (int j = 0; j < 4; ++j) {
                float v = (r < rank) ? acc[m][n][j] * scale : 0.0f;
                xa[(long)(trow + j) * MAXR + r] = f2bf(v);
            }
        }
    }
}

// ------------- main GEMM: 256x256, BK=64, R4 skeleton + counted-lgkm register pipeline -------------
// Skeleton (proven R4/R6): STAGE(t+1) -> vmcnt(8) -> BAR -> compute(t) -> BAR.
// Compute: per-wave read-ahead with COUNTED lgkmcnt waits (never 0 until the last group):
//   issue G1(bfr0+af00,8) G2(af10,4) G3(bfr1+af01,8); lgkm(12)->M1; issue G4(af11,4);
//   lgkm(12)->M2; lgkm(4)->M3; lgkm(0)->M4.  Groups/waits pinned with sched_barrier(0).
// LDS addresses fold to base reg + compile-time offsets (laneByte decomposition).
__launch_bounds__(512, 2)
__global__ void gemm256_kernel(const u16* __restrict__ xb, const u16* __restrict__ wb,
                               const float* __restrict__ bias,
                               const u16* __restrict__ xa, const u16* __restrict__ Bt,
                               const int* __restrict__ b_start_loc,
                               const int* __restrict__ b_adapter_ids,
                               float* __restrict__ out) {
    __shared__ __attribute__((aligned(16))) u16 lds[65536];   // 128 KiB

    // T1: XCD-aware swizzle (nwg=512 % 8 == 0 -> bijective)
    int bid = blockIdx.x;
    int wgid = (bid & 7) * 64 + (bid >> 3);
    int mt = wgid >> 4, nt = wgid & 15;
    int brow = mt * 256, bcol = nt * 256;

    int seg = 0;
    #pragma unroll
    for (int i = 1; i < N_SEQS; ++i) if (b_start_loc[i] <= brow) seg = i;
    int adapter = b_adapter_ids[seg];

    int tid = threadIdx.x;
    int lane = tid & 63, wave = tid >> 6;
    int wm = wave >> 2, wn = wave & 3;       // 2x4 wave grid, per-wave C = 128x64
    int lr = lane & 15, lk = lane >> 4;

    // ---- staging per-thread geometry (linear LDS dest, pre-swizzled source) ----
    int lsw = (tid & 7) ^ ((tid >> 3) & 7);
    int c8  = (lsw & 3) * 8;
    int r0  = (tid >> 3) * 2 + (lsw >> 2);            // q=0 global row; q=1 adds 128
    const long odA0 = (long)(brow + r0) * DIN + c8;           // xb, q=0
    const long odA1 = odA0 + 128L * DIN;                      // xb, q=1
    const long odB0 = (long)(bcol + r0) * DIN + c8;           // wb
    const long odB1 = odB0 + 128L * DIN;
    const long o6A0 = (long)(brow + r0) * MAXR + c8;          // xa (LoRA)
    const long o6A1 = o6A0 + 128L * MAXR;
    const long o6B0 = (long)(adapter * DOUT + bcol + r0) * MAXR + c8;  // Bt
    const long o6B1 = o6B0 + 128L * MAXR;

    #define STAGE_HALF(T, ks, isB, buf)                                            \
        do {                                                                       \
            u16* d = lds + (buf) * 16384 + (ks) * 8192 + ((isB) ? 32768 : 0) + tid * 8; \
            if ((T) < 64) {                                                        \
                long ko = (long)((T) * 64 + (ks) * 32);                            \
                load_lds16(((isB) ? wb + odB0 : xb + odA0) + ko, d);               \
                load_lds16(((isB) ? wb + odB1 : xb + odA1) + ko, d + 4096);        \
            } else {                                                               \
                long ko = (long)((ks) * 32);                                       \
                load_lds16(((isB) ? Bt + o6B0 : xa + o6A0) + ko, d);               \
                load_lds16(((isB) ? Bt + o6B1 : xa + o6A1) + ko, d + 4096);        \
            }                                                                      \
        } while (0)

    #define SB0() __builtin_amdgcn_sched_barrier(0)
    #define BAR() do { __builtin_amdgcn_s_barrier(); SB0(); } while (0)
    #define DSR(d, p, o) (d) = *(const bf16x8*)((p) + (o))

    // lane-invariant byte offset inside a [128 storage-row x 128 B] half-tile
    const int laneByte = (lr >> 1) * 128 + 16 * ((((lr & 1) << 2) + lk) ^ (lr >> 1));
    const char* ldsc = (const char*)lds;
    const int cA = wm * 8192 + laneByte;              // + b*32768
    const int cB = 65536 + wn * 4096 + laneByte;      // + b*32768

    f32x4 acc[8][4] = {};

    // prologue: tile 0 -> buf0
    STAGE_HALF(0, 0, false, 0);
    STAGE_HALF(0, 0, true,  0);
    STAGE_HALF(0, 1, false, 0);
    STAGE_HALF(0, 1, true,  0);

    for (int t = 0; t <= 64; ++t) {
        const int b = t & 1;
        if (t < 64) {
            const int tn = t + 1, bn = tn & 1;
            STAGE_HALF(tn, 0, false, bn);
            STAGE_HALF(tn, 0, true,  bn);
            STAGE_HALF(tn, 1, false, bn);
            STAGE_HALF(tn, 1, true,  bn);
            asm volatile("s_waitcnt vmcnt(8)" ::: "memory");   // tile t landed; t+1 in flight
        } else {
            asm volatile("s_waitcnt vmcnt(0)" ::: "memory");
        }
        BAR();                                   // tile t visible to all waves

        const char* pA = ldsc + (b << 15) + cA;
        const char* pB = ldsc + (b << 15) + cB;

        bf16x8 b0[4], a0[4], a1[4], b1[4], a2[4], a3[4];
        // G1: bfr(ks0) + af(mh0, ks0)  -- 8 reads
        DSR(b0[0], pB, 0);     DSR(b0[1], pB, 1024);  DSR(b0[2], pB, 2048);  DSR(b0[3], pB, 3072);
        DSR(a0[0], pA, 0);     DSR(a0[1], pA, 1024);  DSR(a0[2], pA, 2048);  DSR(a0[3], pA, 3072);
        SB0();
        // G2: af(mh1, ks0) -- 4 reads
        DSR(a1[0], pA, 4096);  DSR(a1[1], pA, 5120);  DSR(a1[2], pA, 6144);  DSR(a1[3], pA, 7168);
        SB0();
        // G3: bfr(ks1) + af(mh0, ks1) -- 8 reads
        DSR(b1[0], pB, 16384); DSR(b1[1], pB, 17408); DSR(b1[2], pB, 18432); DSR(b1[3], pB, 19456);
        DSR(a2[0], pA, 16384); DSR(a2[1], pA, 17408); DSR(a2[2], pA, 18432); DSR(a2[3], pA, 19456);
        SB0();
        // M1 needs G1 only: newest 12 = G2+G3 may be outstanding
        asm volatile("s_waitcnt lgkmcnt(12)" ::: "memory");
        SB0();
        __builtin_amdgcn_s_setprio(1);
        #pragma unroll
        for (int mi = 0; mi < 4; ++mi)
            #pragma unroll
            for (int ni = 0; ni < 4; ++ni)
                acc[mi][ni] = __builtin_amdgcn_mfma_f32_16x16x32_bf16(a0[mi], b0[ni], acc[mi][ni], 0, 0, 0);
        __builtin_amdgcn_s_setprio(0);
        SB0();
        // G4: af(mh1, ks1) -- 4 reads
        DSR(a3[0], pA, 20480); DSR(a3[1], pA, 21504); DSR(a3[2], pA, 22528); DSR(a3[3], pA, 23552);
        SB0();
        // M2 needs G2: newest 12 = G3+G4
        asm volatile("s_waitcnt lgkmcnt(12)" ::: "memory");
        SB0();
        __builtin_amdgcn_s_setprio(1);
        #pragma unroll
        for (int mi = 0; mi < 4; ++mi)
            #pragma unroll
            for (int ni = 0; ni < 4; ++ni)
                acc[4 + mi][ni] = __builtin_amdgcn_mfma_f32_16x16x32_bf16(a1[mi], b0[ni], acc[4 + mi][ni], 0, 0, 0);
        __builtin_amdgcn_s_setprio(0);
        SB0();
        // M3 needs G3: newest 4 = G4
        asm volatile("s_waitcnt lgkmcnt(4)" ::: "memory");
        SB0();
        __builtin_amdgcn_s_setprio(1);
        #pragma unroll
        for (int mi = 0; mi < 4; ++mi)
            #pragma unroll
            for (int ni = 0; ni < 4; ++ni)
                acc[mi][ni] = __builtin_amdgcn_mfma_f32_16x16x32_bf16(a2[mi], b1[ni], acc[mi][ni], 0, 0, 0);
        __builtin_amdgcn_s_setprio(0);
        SB0();
        // M4 needs G4
        asm volatile("s_waitcnt lgkmcnt(0)" ::: "memory");
        SB0();
        __builtin_amdgcn_s_setprio(1);
        #pragma unroll
        for (int mi = 0; mi < 4; ++mi)
            #pragma unroll
            for (int ni = 0; ni < 4; ++ni)
                acc[4 + mi][ni] = __builtin_amdgcn_mfma_f32_16x16x32_bf16(a3[mi], b1[ni], acc[4 + mi][ni], 0, 0, 0);
        __builtin_amdgcn_s_setprio(0);
        SB0();

        BAR();                                   // all waves done reading buf b
    }

    #undef STAGE_HALF
    #undef SB0
    #undef BAR
    #undef DSR

    // ---- epilogue: + bias, fp32 store ----
    #pragma unroll
    for (int m = 0; m < 8; ++m) {
        int orow = brow + wm * 128 + m * 16 + lk * 4;
        #pragma unroll
        for (int n = 0; n < 4; ++n) {
            int ocol = bcol + wn * 64 + n * 16 + lr;
            float bv = bias[ocol];
            #pragma unroll
            for (int j = 0; j < 4; ++j)
                out[(long)(orow + j) * DOUT + ocol] = acc[m][n][j] + bv;
        }
    }
}

extern "C" void kernel_launch(void* const* d_in, const int* in_sizes, int n_in,
                              void* d_out, int out_size, void* d_ws, size_t ws_size,
                              hipStream_t stream) {
    const float* x          = (const float*)d_in[0];
    const float* weight     = (const float*)d_in[1];
    const float* bias       = (const float*)d_in[2];
    const float* a_cache    = (const float*)d_in[3];
    const float* b_cache    = (const float*)d_in[4];
    const int*   b_start    = (const int*)d_in[5];
    const int*   b_adapter  = (const int*)d_in[6];
    const float* b_scaling  = (const float*)d_in[7];
    const int*   rpt        = (const int*)d_in[8];
    const int*   ranks      = (const int*)d_in[9];
    float* out = (float*)d_out;

    char* ws = (char*)d_ws;
    u16* xb = (u16*)ws; ws += (size_t)T_TOK * DIN * 2;          // 64 MiB
    u16* wb = (u16*)ws; ws += (size_t)DOUT * DIN * 2;           // 32 MiB
    u16* ab = (u16*)ws; ws += (size_t)CACHE_LEN * DIN * 2;      // 4 MiB
    u16* Bt = (u16*)ws; ws += (size_t)N_ADPT * DOUT * MAXR * 2; // 4 MiB
    u16* xa = (u16*)ws; ws += (size_t)T_TOK * MAXR * 2;         // 1 MiB

    cvt_kernel<<<2048, 256, 0, stream>>>(x, xb, T_TOK * DIN / 4);
    cvt_kernel<<<2048, 256, 0, stream>>>(weight, wb, DOUT * DIN / 4);
    cvt_kernel<<<512, 256, 0, stream>>>(a_cache, ab, CACHE_LEN * DIN / 4);
    build_bt<<<(N_ADPT * 8 * DOUT) / 256, 256, 0, stream>>>(b_cache, rpt, Bt);
    xa_kernel<<<T_TOK / 128, 256, 0, stream>>>(xb, ab, b_start, b_adapter, b_scaling, rpt, ranks, xa);
    gemm256_kernel<<<(T_TOK / 256) * (DOUT / 256), 512, 0, stream>>>(xb, wb, bias, xa, Bt, b_start, b_adapter, out);
}

// Round 8
// 371.530 us; speedup vs baseline: 1.0981x; 1.0981x over previous
//
#include <hip/hip_runtime.h>
#include <hip/hip_bf16.h>

typedef unsigned short u16;
typedef unsigned int u32;
typedef __attribute__((ext_vector_type(8))) short bf16x8;
typedef __attribute__((ext_vector_type(4))) float f32x4;

#define T_TOK 8192
#define DIN 4096
#define DOUT 4096
#define N_SEQS 4
#define N_ADPT 8
#define MAXR 64
#define CACHE_LEN 512

__device__ __forceinline__ u16 f2bf(float f) {
    u32 u = __builtin_bit_cast(u32, f);
    u += 0x7fffu + ((u >> 16) & 1u);   // RNE
    return (u16)(u >> 16);
}

__device__ __forceinline__ void load_lds16(const u16* g, u16* l) {
    __builtin_amdgcn_global_load_lds(
        (const __attribute__((address_space(1))) u32*)g,
        (__attribute__((address_space(3))) u32*)l, 16, 0, 0);
}

// ---------------- fp32 -> bf16 convert (vectorized) ----------------
__global__ void cvt_kernel(const float* __restrict__ in, u16* __restrict__ out, int n4) {
    int i = blockIdx.x * blockDim.x + threadIdx.x;
    int stride = gridDim.x * blockDim.x;
    for (; i < n4; i += stride) {
        float4 v = reinterpret_cast<const float4*>(in)[i];
        ushort4 o;
        o.x = f2bf(v.x); o.y = f2bf(v.y); o.z = f2bf(v.z); o.w = f2bf(v.w);
        reinterpret_cast<ushort4*>(out)[i] = o;
    }
}

// ------------- build Bt[a][n][r] bf16 from b_cache via page table -------------
__global__ void build_bt(const float* __restrict__ b_cache, const int* __restrict__ rpt,
                         u16* __restrict__ Bt) {
    int id = blockIdx.x * 256 + threadIdx.x;      // total 8*8*4096 = 262144
    int n  = id & (DOUT - 1);
    int rb = (id >> 12) & 7;
    int a  = id >> 15;
    union { u16 u[8]; uint4 v; } pack;
    #pragma unroll
    for (int j = 0; j < 8; ++j) {
        int r = rb * 8 + j;
        int page = rpt[a * MAXR + r];
        pack.u[j] = f2bf(b_cache[(long)page * DOUT + n]);
    }
    *reinterpret_cast<uint4*>(&Bt[((long)(a * DOUT + n)) * MAXR + rb * 8]) = pack.v;
}

// ------------- xa[t][r] = scale * (x[t] . A[page(adapter,r)]), masked -------------
__launch_bounds__(256)
__global__ void xa_kernel(const u16* __restrict__ xb, const u16* __restrict__ ab,
                          const int* __restrict__ b_start_loc,
                          const int* __restrict__ b_adapter_ids,
                          const float* __restrict__ b_scaling,
                          const int* __restrict__ rpt,
                          const int* __restrict__ ranks,
                          u16* __restrict__ xa) {
    int t0 = blockIdx.x * 128;
    int seg = 0;
    #pragma unroll
    for (int i = 1; i < N_SEQS; ++i) if (b_start_loc[i] <= t0) seg = i;
    int adapter = b_adapter_ids[seg];
    float scale = b_scaling[seg];
    int rank = ranks[adapter];

    __shared__ __attribute__((aligned(16))) u16 As[128 * 32];
    __shared__ __attribute__((aligned(16))) u16 Bs[64 * 32];

    int tid = threadIdx.x;
    int lane = tid & 63, wave = tid >> 6;
    int lr = lane & 15, lk = lane >> 4;

    int e0 = wave * 64 + lane;               // [0,256)
    int e1 = 256 + e0;                       // [256,512)
    int ra0 = e0 >> 2, ca0 = (e0 & 3) * 8;
    int ra1 = e1 >> 2, ca1 = (e1 & 3) * 8;
    const u16* gA0 = xb + (long)(t0 + ra0) * DIN + ca0;
    const u16* gA1 = xb + (long)(t0 + ra1) * DIN + ca1;
    int rB = ra0;
    int page = rpt[adapter * MAXR + rB];
    const u16* gB = ab + (long)page * DIN + ca0;

    f32x4 acc[2][4] = {};

    for (int k0 = 0; k0 < DIN; k0 += 32) {
        load_lds16(gA0 + k0, As + wave * 512);
        load_lds16(gA1 + k0, As + 2048 + wave * 512);
        load_lds16(gB + k0,  Bs + wave * 512);
        asm volatile("s_waitcnt vmcnt(0)" ::: "memory");
        __syncthreads();
        bf16x8 af[2], bfr[4];
        #pragma unroll
        for (int m = 0; m < 2; ++m)
            af[m] = *(const bf16x8*)&As[(wave * 32 + m * 16 + lr) * 32 + lk * 8];
        #pragma unroll
        for (int n = 0; n < 4; ++n)
            bfr[n] = *(const bf16x8*)&Bs[(n * 16 + lr) * 32 + lk * 8];
        #pragma unroll
        for (int m = 0; m < 2; ++m)
            #pragma unroll
            for (int n = 0; n < 4; ++n)
                acc[m][n] = __builtin_amdgcn_mfma_f32_16x16x32_bf16(af[m], bfr[n], acc[m][n], 0, 0, 0);
        __syncthreads();
    }

    #pragma unroll
    for (int m = 0; m < 2; ++m) {
        int trow = t0 + wave * 32 + m * 16 + lk * 4;
        #pragma unroll
        for (int n = 0; n < 4; ++n) {
            int r = n * 16 + lr;
            #pragma unroll
            for (int j = 0; j < 4; ++j) {
                float v = (r < rank) ? acc[m][n][j] * scale : 0.0f;
                xa[(long)(trow + j) * MAXR + r] = f2bf(v);
            }
        }
    }
}

// ------------- main GEMM: 256x256, BK=32, 64 KiB LDS -> 2 co-resident blocks/CU -------------
// Mechanism (m114/m97): cross-BLOCK wave overlap. Independent blocks aren't barrier-
// synced; block A's LDS-read phase overlaps block B's MFMA phase. Schedule per tile
// (proven R4): STAGE(t+1, 4 DMA loads) -> vmcnt(4) -> BAR -> compute (12 ds_read_b128,
// 32 MFMA, compiler-scheduled, setprio around MFMA) -> BAR. LoRA = tiles 128,129.
// Staging geometry identical to R6's verified row-pair + XOR-8 swizzle (0 conflicts).
__launch_bounds__(512, 2)
__global__ void gemm256_kernel(const u16* __restrict__ xb, const u16* __restrict__ wb,
                               const float* __restrict__ bias,
                               const u16* __restrict__ xa, const u16* __restrict__ Bt,
                               const int* __restrict__ b_start_loc,
                               const int* __restrict__ b_adapter_ids,
                               float* __restrict__ out) {
    __shared__ __attribute__((aligned(16))) u16 lds[32768];   // 64 KiB: 2 buf x (A 16K + B 16K)

    // T1: XCD-aware swizzle (nwg=512 % 8 == 0 -> bijective)
    int bid = blockIdx.x;
    int wgid = (bid & 7) * 64 + (bid >> 3);
    int mt = wgid >> 4, nt = wgid & 15;
    int brow = mt * 256, bcol = nt * 256;

    int seg = 0;
    #pragma unroll
    for (int i = 1; i < N_SEQS; ++i) if (b_start_loc[i] <= brow) seg = i;
    int adapter = b_adapter_ids[seg];

    int tid = threadIdx.x;
    int lane = tid & 63, wave = tid >> 6;
    int wm = wave >> 2, wn = wave & 3;       // 2x4 wave grid, per-wave C = 128x64
    int lr = lane & 15, lk = lane >> 4;

    // ---- staging geometry (linear LDS dest, pre-swizzled source; R6-verified) ----
    // chunk q*512+tid -> storage row sr = q*64 + (tid>>3) (128 B rows, row-pair packed),
    // phys slot tid&7; logical slot l = (tid&7)^((tid>>3)&7); global row = sr*2 + (l>>2),
    // k-col = (l&3)*8.
    int lsw = (tid & 7) ^ ((tid >> 3) & 7);
    int c8  = (lsw & 3) * 8;
    int r0  = (tid >> 3) * 2 + (lsw >> 2);            // q=0 global row; q=1 adds 128
    const long odA0 = (long)(brow + r0) * DIN + c8;           // xb, q=0
    const long odA1 = odA0 + 128L * DIN;                      // xb, q=1
    const long odB0 = (long)(bcol + r0) * DIN + c8;           // wb
    const long odB1 = odB0 + 128L * DIN;
    const long o6A0 = (long)(brow + r0) * MAXR + c8;          // xa (LoRA)
    const long o6A1 = o6A0 + 128L * MAXR;
    const long o6B0 = (long)(adapter * DOUT + bcol + r0) * MAXR + c8;  // Bt
    const long o6B1 = o6B0 + 128L * MAXR;

    #define STAGE(T, buf)                                                          \
        do {                                                                       \
            u16* dA = lds + (buf) * 8192 + tid * 8;                                \
            u16* dB = lds + 16384 + (buf) * 8192 + tid * 8;                        \
            if ((T) < 128) {                                                       \
                long ko = (long)(T) * 32;                                          \
                load_lds16(xb + odA0 + ko, dA);                                    \
                load_lds16(xb + odA1 + ko, dA + 4096);                             \
                load_lds16(wb + odB0 + ko, dB);                                    \
                load_lds16(wb + odB1 + ko, dB + 4096);                             \
            } else {                                                               \
                long ko = (long)((T) - 128) * 32;                                  \
                load_lds16(xa + o6A0 + ko, dA);                                    \
                load_lds16(xa + o6A1 + ko, dA + 4096);                             \
                load_lds16(Bt + o6B0 + ko, dB);                                    \
                load_lds16(Bt + o6B1 + ko, dB + 4096);                             \
            }                                                                      \
        } while (0)

    // lane-invariant byte offset inside a [128-storage-row x 128 B] tile (R6-verified)
    const int laneByte = (lr >> 1) * 128 + 16 * ((((lr & 1) << 2) + lk) ^ (lr >> 1));
    const char* ldsc = (const char*)lds;
    const int cA = wm * 8192 + laneByte;              // + b*16384 bytes
    const int cB = 32768 + wn * 4096 + laneByte;      // + b*16384 bytes

    f32x4 acc[8][4] = {};

    STAGE(0, 0);                              // prologue: tile 0 -> buf0

    for (int t = 0; t < 130; ++t) {
        const int b = t & 1;
        if (t < 129) {
            STAGE(t + 1, b ^ 1);              // issue next tile's 4 loads first
            asm volatile("s_waitcnt vmcnt(4)" ::: "memory");   // tile t landed; t+1 in flight
        } else {
            asm volatile("s_waitcnt vmcnt(0)" ::: "memory");
        }
        __builtin_amdgcn_s_barrier();          // tile t visible to all waves
        __builtin_amdgcn_sched_barrier(0);

        const char* pA = ldsc + b * 16384 + cA;
        const char* pB = ldsc + b * 16384 + cB;

        bf16x8 bfr[4], af[8];
        #pragma unroll
        for (int ni = 0; ni < 4; ++ni)
            bfr[ni] = *(const bf16x8*)(pB + ni * 1024);
        #pragma unroll
        for (int mi = 0; mi < 8; ++mi)
            af[mi] = *(const bf16x8*)(pA + mi * 1024);

        __builtin_amdgcn_s_setprio(1);         // T5
        #pragma unroll
        for (int mi = 0; mi < 8; ++mi)
            #pragma unroll
            for (int ni = 0; ni < 4; ++ni)
                acc[mi][ni] = __builtin_amdgcn_mfma_f32_16x16x32_bf16(
                    af[mi], bfr[ni], acc[mi][ni], 0, 0, 0);
        __builtin_amdgcn_s_setprio(0);

        if (t < 129) {
            __builtin_amdgcn_s_barrier();      // all waves done reading buf b before overwrite
            __builtin_amdgcn_sched_barrier(0);
        }
    }
    #undef STAGE

    // ---- epilogue: + bias, fp32 store ----
    #pragma unroll
    for (int m = 0; m < 8; ++m) {
        int orow = brow + wm * 128 + m * 16 + lk * 4;
        #pragma unroll
        for (int n = 0; n < 4; ++n) {
            int ocol = bcol + wn * 64 + n * 16 + lr;
            float bv = bias[ocol];
            #pragma unroll
            for (int j = 0; j < 4; ++j)
                out[(long)(orow + j) * DOUT + ocol] = acc[m][n][j] + bv;
        }
    }
}

extern "C" void kernel_launch(void* const* d_in, const int* in_sizes, int n_in,
                              void* d_out, int out_size, void* d_ws, size_t ws_size,
                              hipStream_t stream) {
    const float* x          = (const float*)d_in[0];
    const float* weight     = (const float*)d_in[1];
    const float* bias       = (const float*)d_in[2];
    const float* a_cache    = (const float*)d_in[3];
    const float* b_cache    = (const float*)d_in[4];
    const int*   b_start    = (const int*)d_in[5];
    const int*   b_adapter  = (const int*)d_in[6];
    const float* b_scaling  = (const float*)d_in[7];
    const int*   rpt        = (const int*)d_in[8];
    const int*   ranks      = (const int*)d_in[9];
    float* out = (float*)d_out;

    char* ws = (char*)d_ws;
    u16* xb = (u16*)ws; ws += (size_t)T_TOK * DIN * 2;          // 64 MiB
    u16* wb = (u16*)ws; ws += (size_t)DOUT * DIN * 2;           // 32 MiB
    u16* ab = (u16*)ws; ws += (size_t)CACHE_LEN * DIN * 2;      // 4 MiB
    u16* Bt = (u16*)ws; ws += (size_t)N_ADPT * DOUT * MAXR * 2; // 4 MiB
    u16* xa = (u16*)ws; ws += (size_t)T_TOK * MAXR * 2;         // 1 MiB

    cvt_kernel<<<2048, 256, 0, stream>>>(x, xb, T_TOK * DIN / 4);
    cvt_kernel<<<2048, 256, 0, stream>>>(weight, wb, DOUT * DIN / 4);
    cvt_kernel<<<512, 256, 0, stream>>>(a_cache, ab, CACHE_LEN * DIN / 4);
    build_bt<<<(N_ADPT * 8 * DOUT) / 256, 256, 0, stream>>>(b_cache, rpt, Bt);
    xa_kernel<<<T_TOK / 128, 256, 0, stream>>>(xb, ab, b_start, b_adapter, b_scaling, rpt, ranks, xa);
    gemm256_kernel<<<(T_TOK / 256) * (DOUT / 256), 512, 0, stream>>>(xb, wb, bias, xa, Bt, b_start, b_adapter, out);
}

// Round 9
// 366.913 us; speedup vs baseline: 1.1119x; 1.0126x over previous
//
#include <hip/hip_runtime.h>
#include <hip/hip_bf16.h>

typedef unsigned short u16;
typedef unsigned int u32;
typedef __attribute__((ext_vector_type(8))) short bf16x8;
typedef __attribute__((ext_vector_type(4))) float f32x4;

#define T_TOK 8192
#define DIN 4096
#define DOUT 4096
#define N_SEQS 4
#define N_ADPT 8
#define MAXR 64
#define CACHE_LEN 512

__device__ __forceinline__ u16 f2bf(float f) {
    u32 u = __builtin_bit_cast(u32, f);
    u += 0x7fffu + ((u >> 16) & 1u);   // RNE
    return (u16)(u >> 16);
}

__device__ __forceinline__ void load_lds16(const u16* g, u16* l) {
    __builtin_amdgcn_global_load_lds(
        (const __attribute__((address_space(1))) u32*)g,
        (__attribute__((address_space(3))) u32*)l, 16, 0, 0);
}

// ---------------- fp32 -> bf16 convert (vectorized) ----------------
__global__ void cvt_kernel(const float* __restrict__ in, u16* __restrict__ out, int n4) {
    int i = blockIdx.x * blockDim.x + threadIdx.x;
    int stride = gridDim.x * blockDim.x;
    for (; i < n4; i += stride) {
        float4 v = reinterpret_cast<const float4*>(in)[i];
        ushort4 o;
        o.x = f2bf(v.x); o.y = f2bf(v.y); o.z = f2bf(v.z); o.w = f2bf(v.w);
        reinterpret_cast<ushort4*>(out)[i] = o;
    }
}

// ------------- build Bt[a][n][r] bf16 from b_cache via page table -------------
__global__ void build_bt(const float* __restrict__ b_cache, const int* __restrict__ rpt,
                         u16* __restrict__ Bt) {
    int id = blockIdx.x * 256 + threadIdx.x;      // total 8*8*4096 = 262144
    int n  = id & (DOUT - 1);
    int rb = (id >> 12) & 7;
    int a  = id >> 15;
    union { u16 u[8]; uint4 v; } pack;
    #pragma unroll
    for (int j = 0; j < 8; ++j) {
        int r = rb * 8 + j;
        int page = rpt[a * MAXR + r];
        pack.u[j] = f2bf(b_cache[(long)page * DOUT + n]);
    }
    *reinterpret_cast<uint4*>(&Bt[((long)(a * DOUT + n)) * MAXR + rb * 8]) = pack.v;
}

// ------------- xa[t][r] = scale * (x[t] . A[page(adapter,r)]), masked -------------
__launch_bounds__(256)
__global__ void xa_kernel(const u16* __restrict__ xb, const u16* __restrict__ ab,
                          const int* __restrict__ b_start_loc,
                          const int* __restrict__ b_adapter_ids,
                          const float* __restrict__ b_scaling,
                          const int* __restrict__ rpt,
                          const int* __restrict__ ranks,
                          u16* __restrict__ xa) {
    int t0 = blockIdx.x * 128;
    int seg = 0;
    #pragma unroll
    for (int i = 1; i < N_SEQS; ++i) if (b_start_loc[i] <= t0) seg = i;
    int adapter = b_adapter_ids[seg];
    float scale = b_scaling[seg];
    int rank = ranks[adapter];

    __shared__ __attribute__((aligned(16))) u16 As[128 * 32];
    __shared__ __attribute__((aligned(16))) u16 Bs[64 * 32];

    int tid = threadIdx.x;
    int lane = tid & 63, wave = tid >> 6;
    int lr = lane & 15, lk = lane >> 4;

    int e0 = wave * 64 + lane;               // [0,256)
    int e1 = 256 + e0;                       // [256,512)
    int ra0 = e0 >> 2, ca0 = (e0 & 3) * 8;
    int ra1 = e1 >> 2, ca1 = (e1 & 3) * 8;
    const u16* gA0 = xb + (long)(t0 + ra0) * DIN + ca0;
    const u16* gA1 = xb + (long)(t0 + ra1) * DIN + ca1;
    int rB = ra0;
    int page = rpt[adapter * MAXR + rB];
    const u16* gB = ab + (long)page * DIN + ca0;

    f32x4 acc[2][4] = {};

    for (int k0 = 0; k0 < DIN; k0 += 32) {
        load_lds16(gA0 + k0, As + wave * 512);
        load_lds16(gA1 + k0, As + 2048 + wave * 512);
        load_lds16(gB + k0,  Bs + wave * 512);
        asm volatile("s_waitcnt vmcnt(0)" ::: "memory");
        __syncthreads();
        bf16x8 af[2], bfr[4];
        #pragma unroll
        for (int m = 0; m < 2; ++m)
            af[m] = *(const bf16x8*)&As[(wave * 32 + m * 16 + lr) * 32 + lk * 8];
        #pragma unroll
        for (int n = 0; n < 4; ++n)
            bfr[n] = *(const bf16x8*)&Bs[(n * 16 + lr) * 32 + lk * 8];
        #pragma unroll
        for (int m = 0; m < 2; ++m)
            #pragma unroll
            for (int n = 0; n < 4; ++n)
                acc[m][n] = __builtin_amdgcn_mfma_f32_16x16x32_bf16(af[m], bfr[n], acc[m][n], 0, 0, 0);
        __syncthreads();
    }

    #pragma unroll
    for (int m = 0; m < 2; ++m) {
        int trow = t0 + wave * 32 + m * 16 + lk * 4;
        #pragma unroll
        for (int n = 0; n < 4; ++n) {
            int r = n * 16 + lr;
            #pragma unroll
            for (int j = 0; j < 4; ++j) {
                float v = (r < rank) ? acc[m][n][j] * scale : 0.0f;
                xa[(long)(trow + j) * MAXR + r] = f2bf(v);
            }
        }
    }
}

// ------------- main GEMM: 256x256, BK=32, register-pipelined fragments -------------
// Key change vs R8: MFMA(tile t) consumes fragments PRELOADED during interval t-1;
// this interval's ds_reads fill the OTHER register set with tile t+1's fragments.
// Reads and MFMAs in one interval are independent -> both pipes pressured at once.
// Two named frag sets, static even/odd unroll (no runtime indexing). Safety:
// lgkmcnt(0)+sched_barrier+s_barrier at interval end (reads drained before the
// next DMA overwrite); vmcnt(4) counted exactly (prologue stages t0,t1; steady
// state retires tile t+1; ghost-clamped tail). LoRA = K-tiles 128,129.
__launch_bounds__(512, 2)
__global__ void gemm256_kernel(const u16* __restrict__ xb, const u16* __restrict__ wb,
                               const float* __restrict__ bias,
                               const u16* __restrict__ xa, const u16* __restrict__ Bt,
                               const int* __restrict__ b_start_loc,
                               const int* __restrict__ b_adapter_ids,
                               float* __restrict__ out) {
    __shared__ __attribute__((aligned(16))) u16 lds[32768];   // 64 KiB: 2 buf x (A 8K + B 8K u16)

    // T1: XCD-aware swizzle (nwg=512 % 8 == 0 -> bijective)
    int bid = blockIdx.x;
    int wgid = (bid & 7) * 64 + (bid >> 3);
    int mt = wgid >> 4, nt = wgid & 15;
    int brow = mt * 256, bcol = nt * 256;

    int seg = 0;
    #pragma unroll
    for (int i = 1; i < N_SEQS; ++i) if (b_start_loc[i] <= brow) seg = i;
    int adapter = b_adapter_ids[seg];

    int tid = threadIdx.x;
    int lane = tid & 63, wave = tid >> 6;
    int wm = wave >> 2, wn = wave & 3;       // 2x4 wave grid, per-wave C = 128x64
    int lr = lane & 15, lk = lane >> 4;

    // ---- staging geometry (linear LDS dest, pre-swizzled source; R6/R8-verified) ----
    int lsw = (tid & 7) ^ ((tid >> 3) & 7);
    int c8  = (lsw & 3) * 8;
    int r0  = (tid >> 3) * 2 + (lsw >> 2);            // q=0 global row; q=1 adds 128
    const long odA0 = (long)(brow + r0) * DIN + c8;           // xb, q=0
    const long odA1 = odA0 + 128L * DIN;                      // xb, q=1
    const long odB0 = (long)(bcol + r0) * DIN + c8;           // wb
    const long odB1 = odB0 + 128L * DIN;
    const long o6A0 = (long)(brow + r0) * MAXR + c8;          // xa (LoRA)
    const long o6A1 = o6A0 + 128L * MAXR;
    const long o6B0 = (long)(adapter * DOUT + bcol + r0) * MAXR + c8;  // Bt
    const long o6B1 = o6B0 + 128L * MAXR;

    #define STAGE(T, buf)                                                          \
        do {                                                                       \
            u16* dA = lds + (buf) * 8192 + tid * 8;                                \
            u16* dB = lds + 16384 + (buf) * 8192 + tid * 8;                        \
            if ((T) < 128) {                                                       \
                long ko = (long)(T) * 32;                                          \
                load_lds16(xb + odA0 + ko, dA);                                    \
                load_lds16(xb + odA1 + ko, dA + 4096);                             \
                load_lds16(wb + odB0 + ko, dB);                                    \
                load_lds16(wb + odB1 + ko, dB + 4096);                             \
            } else {                                                               \
                long ko = (long)((T) - 128) * 32;                                  \
                load_lds16(xa + o6A0 + ko, dA);                                    \
                load_lds16(xa + o6A1 + ko, dA + 4096);                             \
                load_lds16(Bt + o6B0 + ko, dB);                                    \
                load_lds16(Bt + o6B1 + ko, dB + 4096);                             \
            }                                                                      \
        } while (0)

    // lane-invariant byte offset inside a [64-storage-row x 128 B] tile (R6-verified)
    const int laneByte = (lr >> 1) * 128 + 16 * ((((lr & 1) << 2) + lk) ^ (lr >> 1));
    const char* ldsc = (const char*)lds;
    const int cA = wm * 8192 + laneByte;              // + buf*16384 bytes
    const int cB = 32768 + wn * 4096 + laneByte;      // + buf*16384 bytes

    #define READF(FA, FB, par)                                                     \
        do {                                                                       \
            const char* pA = ldsc + (par) * 16384 + cA;                            \
            const char* pB = ldsc + (par) * 16384 + cB;                            \
            _Pragma("unroll")                                                      \
            for (int ni = 0; ni < 4; ++ni) FB[ni] = *(const bf16x8*)(pB + ni * 1024); \
            _Pragma("unroll")                                                      \
            for (int mi = 0; mi < 8; ++mi) FA[mi] = *(const bf16x8*)(pA + mi * 1024); \
        } while (0)

    #define MFMA32(FA, FB)                                                         \
        do {                                                                       \
            __builtin_amdgcn_s_setprio(1);                                         \
            _Pragma("unroll")                                                      \
            for (int mi = 0; mi < 8; ++mi)                                         \
                _Pragma("unroll")                                                  \
                for (int ni = 0; ni < 4; ++ni)                                     \
                    acc[mi][ni] = __builtin_amdgcn_mfma_f32_16x16x32_bf16(         \
                        FA[mi], FB[ni], acc[mi][ni], 0, 0, 0);                     \
            __builtin_amdgcn_s_setprio(0);                                         \
        } while (0)

    #define ENDBAR()                                                               \
        do {                                                                       \
            asm volatile("s_waitcnt lgkmcnt(0)" ::: "memory");                     \
            __builtin_amdgcn_sched_barrier(0);                                     \
            __builtin_amdgcn_s_barrier();                                          \
        } while (0)

    f32x4 acc[8][4] = {};
    bf16x8 fA0[8], fB0[4], fA1[8], fB1[4];

    // ---- prologue: stage tiles 0,1; preload tile-0 fragments ----
    STAGE(0, 0);
    STAGE(1, 1);
    asm volatile("s_waitcnt vmcnt(4)" ::: "memory");   // tile0 landed; tile1 in flight
    __builtin_amdgcn_s_barrier();
    READF(fA0, fB0, 0);
    ENDBAR();

    for (int t = 0; t < 130; t += 2) {
        // ---- even half: consume set0 (tile t), preload set1 (tile t+1) ----
        STAGE((t + 2 < 130) ? t + 2 : 129, t & 1);     // buf[t&1]: tile t's frags already in regs
        asm volatile("s_waitcnt vmcnt(4)" ::: "memory"); // tile t+1 landed; t+2 in flight
        __builtin_amdgcn_s_barrier();                   // CU-wide: t+1 visible
        READF(fA1, fB1, (t + 1) & 1);                   // independent of MFMA below
        MFMA32(fA0, fB0);
        ENDBAR();                                       // my reads drained before next DMA

        // ---- odd half: consume set1 (tile t+1), preload set0 (tile t+2) ----
        STAGE((t + 3 < 130) ? t + 3 : 129, (t + 1) & 1);
        asm volatile("s_waitcnt vmcnt(4)" ::: "memory");
        __builtin_amdgcn_s_barrier();
        if (t + 2 < 130) READF(fA0, fB0, t & 1);
        MFMA32(fA1, fB1);
        ENDBAR();
    }
    asm volatile("s_waitcnt vmcnt(0)" ::: "memory");   // drain ghost DMAs

    #undef STAGE
    #undef READF
    #undef MFMA32
    #undef ENDBAR

    // ---- epilogue: + bias, fp32 store ----
    #pragma unroll
    for (int m = 0; m < 8; ++m) {
        int orow = brow + wm * 128 + m * 16 + lk * 4;
        #pragma unroll
        for (int n = 0; n < 4; ++n) {
            int ocol = bcol + wn * 64 + n * 16 + lr;
            float bv = bias[ocol];
            #pragma unroll
            for (int j = 0; j < 4; ++j)
                out[(long)(orow + j) * DOUT + ocol] = acc[m][n][j] + bv;
        }
    }
}

extern "C" void kernel_launch(void* const* d_in, const int* in_sizes, int n_in,
                              void* d_out, int out_size, void* d_ws, size_t ws_size,
                              hipStream_t stream) {
    const float* x          = (const float*)d_in[0];
    const float* weight     = (const float*)d_in[1];
    const float* bias       = (const float*)d_in[2];
    const float* a_cache    = (const float*)d_in[3];
    const float* b_cache    = (const float*)d_in[4];
    const int*   b_start    = (const int*)d_in[5];
    const int*   b_adapter  = (const int*)d_in[6];
    const float* b_scaling  = (const float*)d_in[7];
    const int*   rpt        = (const int*)d_in[8];
    const int*   ranks      = (const int*)d_in[9];
    float* out = (float*)d_out;

    char* ws = (char*)d_ws;
    u16* xb = (u16*)ws; ws += (size_t)T_TOK * DIN * 2;          // 64 MiB
    u16* wb = (u16*)ws; ws += (size_t)DOUT * DIN * 2;           // 32 MiB
    u16* ab = (u16*)ws; ws += (size_t)CACHE_LEN * DIN * 2;      // 4 MiB
    u16* Bt = (u16*)ws; ws += (size_t)N_ADPT * DOUT * MAXR * 2; // 4 MiB
    u16* xa = (u16*)ws; ws += (size_t)T_TOK * MAXR * 2;         // 1 MiB

    cvt_kernel<<<2048, 256, 0, stream>>>(x, xb, T_TOK * DIN / 4);
    cvt_kernel<<<2048, 256, 0, stream>>>(weight, wb, DOUT * DIN / 4);
    cvt_kernel<<<512, 256, 0, stream>>>(a_cache, ab, CACHE_LEN * DIN / 4);
    build_bt<<<(N_ADPT * 8 * DOUT) / 256, 256, 0, stream>>>(b_cache, rpt, Bt);
    xa_kernel<<<T_TOK / 128, 256, 0, stream>>>(xb, ab, b_start, b_adapter, b_scaling, rpt, ranks, xa);
    gemm256_kernel<<<(T_TOK / 256) * (DOUT / 256), 512, 0, stream>>>(xb, wb, bias, xa, Bt, b_start, b_adapter, out);
}